// Round 6
// baseline (237.923 us; speedup 1.0000x reference)
//
#include <hip/hip_runtime.h>

#define B_ 4
#define C_ 256
#define L_ 4096
#define NG 32
#define CPG 8
#define BL (B_ * L_)               // 16384 token rows
#define KPART 4
#define KEYS_PP (L_ / KPART)       // 1024 keys per partition
#define NIT (KEYS_PP / 32)         // 32 iterations of 32 keys
#define QLOG2E 0.09016844f         // C^-0.5 * log2(e), folded into q_w/q_b

typedef __attribute__((ext_vector_type(8))) __bf16 bf16x8;
typedef __attribute__((ext_vector_type(8))) short s16x8;
typedef __attribute__((ext_vector_type(4))) float f32x4;
typedef __attribute__((ext_vector_type(16))) float f32x16;

__device__ __forceinline__ unsigned short f2bf(float f) {
  unsigned int u = __builtin_bit_cast(unsigned int, f);
  u += 0x7fffu + ((u >> 16) & 1u);
  return (unsigned short)(u >> 16);
}
__device__ __forceinline__ float bf2f(unsigned short u) {
  unsigned int v = ((unsigned int)u) << 16;
  return __builtin_bit_cast(float, v);
}
#if __has_builtin(__builtin_amdgcn_exp2f)
#define EXP2F(x) __builtin_amdgcn_exp2f(x)
#else
#define EXP2F(x) exp2f(x)
#endif

// async global->LDS, 16B/lane; dest = ldsbase + lane*16 (wave-uniform base)
__device__ __forceinline__ void gld_lds16(const void* g, void* l) {
  __builtin_amdgcn_global_load_lds(
      (const __attribute__((address_space(1))) unsigned int*)g,
      (__attribute__((address_space(3))) unsigned int*)l, 16, 0, 0);
}

// sum-reduce over each 16-lane group via DPP
__device__ __forceinline__ float red16_add(float x) {
  int i;
  i = __builtin_amdgcn_update_dpp(0, __builtin_bit_cast(int, x), 0xB1, 0xF, 0xF, false);
  x += __builtin_bit_cast(float, i);
  i = __builtin_amdgcn_update_dpp(0, __builtin_bit_cast(int, x), 0x4E, 0xF, 0xF, false);
  x += __builtin_bit_cast(float, i);
  i = __builtin_amdgcn_update_dpp(0, __builtin_bit_cast(int, x), 0x124, 0xF, 0xF, false);
  x += __builtin_bit_cast(float, i);
  i = __builtin_amdgcn_update_dpp(0, __builtin_bit_cast(int, x), 0x128, 0xF, 0xF, false);
  x += __builtin_bit_cast(float, i);
  return x;
}

// ------- init: weight cvt (blocks 0..127) + GN stats (blocks 128..255) -------
__global__ __launch_bounds__(256) void init_k(const float* __restrict__ qw,
                                              const float* __restrict__ kw,
                                              const float* __restrict__ vw,
                                              const float* __restrict__ pw,
                                              const float* __restrict__ qb,
                                              const float* __restrict__ x,
                                              unsigned short* __restrict__ wq,
                                              unsigned short* __restrict__ wk,
                                              unsigned short* __restrict__ wv,
                                              unsigned short* __restrict__ wp,
                                              float* __restrict__ qbs,
                                              float* __restrict__ stats) {
  const int bid = blockIdx.x;
  const int t = threadIdx.x;
  if (bid < 128) {
    const int m = bid >> 5;
    const int blk = bid & 31;
    const float* src = (m == 0) ? qw : (m == 1) ? kw : (m == 2) ? vw : pw;
    unsigned short* dst = (m == 0) ? wq : (m == 1) ? wk : (m == 2) ? wv : wp;
    const float sc = (m == 0) ? QLOG2E : 1.0f;
    const int base = (blk * 256 + t) * 8;
    f32x4 a = *(const f32x4*)(src + base);
    f32x4 b = *(const f32x4*)(src + base + 4);
    s16x8 o;
#pragma unroll
    for (int j = 0; j < 4; ++j) {
      o[j] = (short)f2bf(a[j] * sc);
      o[4 + j] = (short)f2bf(b[j] * sc);
    }
    *(s16x8*)(dst + base) = o;
    if (m == 0 && blk == 0) qbs[t] = qb[t] * QLOG2E;
  } else {
    const int bg = bid - 128;
    const float* base = x + (size_t)bg * (CPG * L_);
    float s = 0.f, ss = 0.f;
#pragma unroll
    for (int i = 0; i < 32; ++i) {
      f32x4 v = *(const f32x4*)(base + (size_t)(t + i * 256) * 4);
#pragma unroll
      for (int j = 0; j < 4; ++j) { s += v[j]; ss += v[j] * v[j]; }
    }
#pragma unroll
    for (int d = 1; d < 64; d <<= 1) {
      s += __shfl_xor(s, d, 64);
      ss += __shfl_xor(ss, d, 64);
    }
    __shared__ float red[8];
    if ((t & 63) == 0) { red[(t >> 6) * 2] = s; red[(t >> 6) * 2 + 1] = ss; }
    __syncthreads();
    if (t == 0) {
      float S = red[0] + red[2] + red[4] + red[6];
      float SS = red[1] + red[3] + red[5] + red[7];
      const float inv_n = 1.f / (float)(CPG * L_);
      float mean = S * inv_n;
      float var = SS * inv_n - mean * mean;
      stats[bg * 2] = mean;
      stats[bg * 2 + 1] = rsqrtf(var + 1e-6f);
    }
  }
}

// ------------- GroupNorm apply + transpose -> ht[B*L, C] bf16 -------------
__global__ __launch_bounds__(256) void gn_apply_k(const float* __restrict__ x,
                                                  const float* __restrict__ stats,
                                                  const float* __restrict__ gam,
                                                  const float* __restrict__ bet,
                                                  unsigned short* __restrict__ ht) {
  __shared__ unsigned short tile[64 * 256];
  const int blk = blockIdx.x;
  const int b = blk >> 6;
  const int l0 = (blk & 63) * 64;
  const int t = threadIdx.x;
  const int c = t;
  const float mean = stats[(b * NG + (c >> 3)) * 2];
  const float rstd = stats[(b * NG + (c >> 3)) * 2 + 1];
  const float sc = rstd * gam[c];
  const float sb = bet[c] - mean * sc;
  const float* row = x + ((size_t)(b * C_ + c)) * L_ + l0;
#pragma unroll
  for (int v = 0; v < 16; ++v) {
    f32x4 f = *(const f32x4*)(row + v * 4);
#pragma unroll
    for (int j = 0; j < 4; ++j) tile[(v * 4 + j) * 256 + c] = f2bf(f[j] * sc + sb);
  }
  __syncthreads();
#pragma unroll
  for (int i = 0; i < 8; ++i) {
    int id = t + i * 256;
    int l = id >> 5, off = id & 31;
    *(s16x8*)(ht + ((size_t)(b * L_) + l0 + l) * 256 + off * 8) =
        *(const s16x8*)(tile + l * 256 + off * 8);
  }
}

// ---- QKV fused: z=0 Q->qt rows, z=1 K->kt rows, z=2 V->vg slot-permuted tiles ----
__global__ __launch_bounds__(256) void qkv_k(const unsigned short* __restrict__ ht,
                                             const unsigned short* __restrict__ wq,
                                             const unsigned short* __restrict__ wk,
                                             const unsigned short* __restrict__ wv,
                                             const float* __restrict__ qbs,
                                             const float* __restrict__ kbias,
                                             const float* __restrict__ vbias,
                                             unsigned short* __restrict__ qt,
                                             unsigned short* __restrict__ kt,
                                             unsigned short* __restrict__ vg) {
  __shared__ unsigned short Al[64 * 256];
  __shared__ unsigned short Wl[64 * 256];
  const int z = blockIdx.z;
  const unsigned short* W = (z == 0) ? wq : (z == 1) ? wk : wv;
  const float* bias = (z == 0) ? qbs : (z == 1) ? kbias : vbias;
  const int m0 = blockIdx.x * 64;
  const int n0 = blockIdx.y * 64;
  const int t = threadIdx.x;
  const int w = t >> 6, lane = t & 63, l15 = lane & 15, q = lane >> 4;
#pragma unroll
  for (int i = 0; i < 8; ++i) {
    const int seg = w * 8 + i;
    const int idx = seg * 64 + lane;
    const int row = idx >> 5, c16 = idx & 31;
    gld_lds16(ht + (size_t)(m0 + row) * 256 + ((c16 ^ (row & 7)) * 8), Al + seg * 512);
    gld_lds16(W + (size_t)(n0 + row) * 256 + ((c16 ^ (row & 7)) * 8), Wl + seg * 512);
  }
  __syncthreads();
  bf16x8 af[8];
#pragma unroll
  for (int kf = 0; kf < 8; ++kf) {
    int row = w * 16 + l15;
    af[kf] = *(const bf16x8*)(Al + row * 256 + (((kf * 4 + q) ^ (row & 7)) * 8));
  }
  f32x4 acc[4];
#pragma unroll
  for (int nf = 0; nf < 4; ++nf) {
    f32x4 cacc = {0.f, 0.f, 0.f, 0.f};
#pragma unroll
    for (int kf = 0; kf < 8; ++kf) {
      int row = nf * 16 + l15;
      bf16x8 bf = *(const bf16x8*)(Wl + row * 256 + (((kf * 4 + q) ^ (row & 7)) * 8));
      cacc = __builtin_amdgcn_mfma_f32_16x16x32_bf16(af[kf], bf, cacc, 0, 0, 0);
    }
    acc[nf] = cacc;
  }
  unsigned short* Ct = (z == 0) ? qt : kt;
#pragma unroll
  for (int nf = 0; nf < 4; ++nf) {
    const int n = n0 + nf * 16 + l15;
    const float bs = bias[n];
#pragma unroll
    for (int r = 0; r < 4; ++r) {
      const int m = m0 + w * 16 + q * 4 + r;
      const float v = acc[nf][r] + bs;
      if (z < 2) {
        Ct[(size_t)m * 256 + n] = f2bf(v);
      } else {
        // V tile layout: [b][jt(32-key tiles)][c][slot], slot=(j&15)*2+(j>>4)
        const int b = m >> 12, i = m & (L_ - 1);
        const int jt = i >> 5, j = i & 31;
        const int slot = (j & 15) * 2 + (j >> 4);
        vg[((size_t)(b * 128 + jt)) * 8192 + n * 32 + slot] = f2bf(v);
      }
    }
  }
}

// ------- Flash attention v6: 128 q/block, deferred channel-split PV, V in regs -------
// Qt,Kt: [B*L, C] bf16 rows (Q pre-scaled by QLOG2E); Vg: slot-permuted 32-key tiles.
// p = exp2(s); partial O (unnormalized) + row-sums l per partition.
__global__ __launch_bounds__(256, 2) void attn_k(const unsigned short* __restrict__ Qt,
                                                 const unsigned short* __restrict__ Kt,
                                                 const unsigned short* __restrict__ Vg,
                                                 unsigned short* __restrict__ o0p,
                                                 unsigned short* __restrict__ o1p,
                                                 unsigned short* __restrict__ o2p,
                                                 unsigned short* __restrict__ o3p,
                                                 float* __restrict__ ml) {
  __shared__ unsigned short Kl[32 * 256];   // 16 KB [keyrow][chunk ^ (row&7)]
  __shared__ unsigned int Pb[2][4][32][20]; // P dbuf: [buf][wave][q-row][b32 slot-pair]
  const int bid = blockIdx.x;
  const int g = bid & 15;                   // co-locates (b,part) per XCD
  const int b = g >> 2, part = g & 3;
  const int qi = bid >> 4;                  // 0..31 q-tile within batch
  const int t = threadIdx.x;
  const int w = t >> 6, lane = t & 63;
  const int l15 = lane & 15, q = lane >> 4;
  const int l31 = lane & 31, h = lane >> 5;

  const int qb0 = b * L_ + qi * 128;
  const int qrow0 = qb0 + w * 32;           // wave's first query row (global)
  bf16x8 qf[2][8];
#pragma unroll
  for (int mi = 0; mi < 2; ++mi)
#pragma unroll
    for (int kf = 0; kf < 8; ++kf)
      qf[mi][kf] =
          *(const bf16x8*)(Qt + ((size_t)(qrow0 + mi * 16 + l15)) * 256 + kf * 32 + q * 8);

  // oacc[qt2*2+nf]: queries qt2*32.., channels w*64 + nf*32 + l31 (channel-split)
  f32x16 oacc[8];
#pragma unroll
  for (int nf = 0; nf < 8; ++nf)
#pragma unroll
    for (int gg = 0; gg < 16; ++gg) oacc[nf][gg] = 0.f;
  float ls0[4] = {0.f, 0.f, 0.f, 0.f}, ls1[4] = {0.f, 0.f, 0.f, 0.f};

  const unsigned short* kbase = Kt + ((size_t)(b * L_ + part * KEYS_PP)) * 256;
  const unsigned short* vbase = Vg + ((size_t)(b * 128 + part * 32)) * 8192;

  // prologue: stage K_0
#pragma unroll
  for (int i = 0; i < 4; ++i) {
    const int seg = w * 4 + i;
    const int idx = seg * 64 + lane;
    const int row = idx >> 5, c16 = idx & 31;
    gld_lds16(kbase + (size_t)row * 256 + ((c16 ^ (row & 7)) * 8), Kl + seg * 512);
  }

  for (int it = 0; it < NIT; ++it) {
    __syncthreads();   // (A): K_it staged (vmcnt drained); P_{it-1} visible
    // V for tile it-1 (deferred PV), straight to registers
    bf16x8 va[2][2];
    if (it > 0) {
      const unsigned short* vt = vbase + (size_t)(it - 1) * 8192;
#pragma unroll
      for (int nf = 0; nf < 2; ++nf)
#pragma unroll
        for (int kc = 0; kc < 2; ++kc)
          va[nf][kc] = *(const bf16x8*)(vt + (w * 64 + nf * 32 + l31) * 32 +
                                        kc * 16 + h * 8);
    }
    // QK^T: wave's 32 queries x 32 keys
    f32x4 s00 = {0.f, 0.f, 0.f, 0.f}, s01 = s00, s10 = s00, s11 = s00;
#pragma unroll
    for (int kf = 0; kf < 8; ++kf) {
      const int ch = ((kf * 4 + q) ^ (l15 & 7)) * 8;
      bf16x8 kb0 = *(const bf16x8*)(Kl + l15 * 256 + ch);
      bf16x8 kb1 = *(const bf16x8*)(Kl + (16 + l15) * 256 + ch);
      s00 = __builtin_amdgcn_mfma_f32_16x16x32_bf16(qf[0][kf], kb0, s00, 0, 0, 0);
      s01 = __builtin_amdgcn_mfma_f32_16x16x32_bf16(qf[0][kf], kb1, s01, 0, 0, 0);
      s10 = __builtin_amdgcn_mfma_f32_16x16x32_bf16(qf[1][kf], kb0, s10, 0, 0, 0);
      s11 = __builtin_amdgcn_mfma_f32_16x16x32_bf16(qf[1][kf], kb1, s11, 0, 0, 0);
    }
    // p = exp2(s); pack (key l15, key 16+l15) -> one b32 at slot-pair l15
    const int buf = it & 1;
#pragma unroll
    for (int r = 0; r < 4; ++r) {
      float p00 = EXP2F(s00[r]), p01 = EXP2F(s01[r]);
      float p10 = EXP2F(s10[r]), p11 = EXP2F(s11[r]);
      ls0[r] += p00 + p01;
      ls1[r] += p10 + p11;
      Pb[buf][w][q * 4 + r][l15] = (unsigned int)f2bf(p00) | ((unsigned int)f2bf(p01) << 16);
      Pb[buf][w][16 + q * 4 + r][l15] =
          (unsigned int)f2bf(p10) | ((unsigned int)f2bf(p11) << 16);
    }
    __syncthreads();   // (B): QK reads of Kl done; P_it written
    if (it + 1 < NIT) {
      const unsigned short* ksrc = kbase + (size_t)((it + 1) * 32) * 256;
#pragma unroll
      for (int i = 0; i < 4; ++i) {
        const int seg = w * 4 + i;
        const int idx = seg * 64 + lane;
        const int row = idx >> 5, c16 = idx & 31;
        gld_lds16(ksrc + (size_t)row * 256 + ((c16 ^ (row & 7)) * 8), Kl + seg * 512);
      }
    }
    // PV_{it-1}: all 128 q x wave's 64 channels (V from regs, P from LDS)
    if (it > 0) {
      const int pbuf = (it - 1) & 1;
#pragma unroll
      for (int qt2 = 0; qt2 < 4; ++qt2) {
        bf16x8 pa0 = *(const bf16x8*)&Pb[pbuf][qt2][l31][h * 4];
        bf16x8 pa1 = *(const bf16x8*)&Pb[pbuf][qt2][l31][8 + h * 4];
#pragma unroll
        for (int nf = 0; nf < 2; ++nf) {
          oacc[qt2 * 2 + nf] =
              __builtin_amdgcn_mfma_f32_32x32x16_bf16(pa0, va[nf][0], oacc[qt2 * 2 + nf], 0, 0, 0);
          oacc[qt2 * 2 + nf] =
              __builtin_amdgcn_mfma_f32_32x32x16_bf16(pa1, va[nf][1], oacc[qt2 * 2 + nf], 0, 0, 0);
        }
      }
    }
  }
  // epilogue PV for tile NIT-1 (P visible after last (B))
  {
    bf16x8 va[2][2];
    const unsigned short* vt = vbase + (size_t)(NIT - 1) * 8192;
#pragma unroll
    for (int nf = 0; nf < 2; ++nf)
#pragma unroll
      for (int kc = 0; kc < 2; ++kc)
        va[nf][kc] =
            *(const bf16x8*)(vt + (w * 64 + nf * 32 + l31) * 32 + kc * 16 + h * 8);
    const int pbuf = (NIT - 1) & 1;
#pragma unroll
    for (int qt2 = 0; qt2 < 4; ++qt2) {
      bf16x8 pa0 = *(const bf16x8*)&Pb[pbuf][qt2][l31][h * 4];
      bf16x8 pa1 = *(const bf16x8*)&Pb[pbuf][qt2][l31][8 + h * 4];
#pragma unroll
      for (int nf = 0; nf < 2; ++nf) {
        oacc[qt2 * 2 + nf] =
            __builtin_amdgcn_mfma_f32_32x32x16_bf16(pa0, va[nf][0], oacc[qt2 * 2 + nf], 0, 0, 0);
        oacc[qt2 * 2 + nf] =
            __builtin_amdgcn_mfma_f32_32x32x16_bf16(pa1, va[nf][1], oacc[qt2 * 2 + nf], 0, 0, 0);
      }
    }
  }

  // write partial O: wave w owns channels [w*64, w*64+64) for all 128 q
  unsigned short* opb = (part == 0) ? o0p : (part == 1) ? o1p : (part == 2) ? o2p : o3p;
#pragma unroll
  for (int qt2 = 0; qt2 < 4; ++qt2)
#pragma unroll
    for (int nf = 0; nf < 2; ++nf)
#pragma unroll
      for (int gg = 0; gg < 16; ++gg) {
        const int row = qt2 * 32 + (gg & 3) + 8 * (gg >> 2) + 4 * h;
        opb[(size_t)(qb0 + row) * 256 + w * 64 + nf * 32 + l31] =
            f2bf(oacc[qt2 * 2 + nf][gg]);
      }
  // row-sums (wave's own 32 queries)
#pragma unroll
  for (int r = 0; r < 4; ++r) {
    ls0[r] = red16_add(ls0[r]);
    ls1[r] = red16_add(ls1[r]);
  }
  if (l15 == 0) {
    float* mlp = ml + (size_t)part * BL;
#pragma unroll
    for (int r = 0; r < 4; ++r) {
      mlp[qrow0 + q * 4 + r] = ls0[r];
      mlp[qrow0 + 16 + q * 4 + r] = ls1[r];
    }
  }
}

// ------------- merge 4 partials -> Om [B*L, C] bf16 (fallback path) -------------
__global__ __launch_bounds__(256) void merge_k(const unsigned short* __restrict__ o0p,
                                               const unsigned short* __restrict__ o1p,
                                               const unsigned short* __restrict__ o2p,
                                               const unsigned short* __restrict__ o3p,
                                               const float* __restrict__ ml,
                                               unsigned short* __restrict__ Om) {
  const int row = blockIdx.x * 8 + (threadIdx.x >> 5);
  const int c8 = threadIdx.x & 31;
  const float inv = 1.0f / (ml[row] + ml[BL + row] + ml[2 * BL + row] + ml[3 * BL + row]);
  const size_t off = (size_t)row * 256 + c8 * 8;
  s16x8 v0 = *(const s16x8*)(o0p + off);
  s16x8 v1 = *(const s16x8*)(o1p + off);
  s16x8 v2 = *(const s16x8*)(o2p + off);
  s16x8 v3 = *(const s16x8*)(o3p + off);
  s16x8 o;
#pragma unroll
  for (int j = 0; j < 8; ++j)
    o[j] = (short)f2bf((bf2f((unsigned short)v0[j]) + bf2f((unsigned short)v1[j]) +
                        bf2f((unsigned short)v2[j]) + bf2f((unsigned short)v3[j])) *
                       inv);
  *(s16x8*)(Om + off) = o;
}

// ---- proj: out[b,o,i] = x + bias[o] + (sum over NP partials of W·Op_p)[o,i] * scale_i ----
// FUSED=1: X = opcat [4][BL][256], scale_i = 1/sum(l); FUSED=0: X = merged Om, scale=1.
template <int FUSED>
__global__ __launch_bounds__(256) void proj_k(const unsigned short* __restrict__ X,
                                              const unsigned short* __restrict__ W,
                                              const float* __restrict__ bias,
                                              const float* __restrict__ xres,
                                              const float* __restrict__ ml,
                                              float* __restrict__ out) {
  __shared__ unsigned short Wl[64 * 256];
  __shared__ unsigned short Xl[64 * 256];
  const int i0 = blockIdx.x * 64;
  const int o0 = blockIdx.y * 64;
  const int b = blockIdx.z;
  const int t = threadIdx.x;
  const int w = t >> 6, lane = t & 63, l15 = lane & 15, q = lane >> 4;
  const int NP = FUSED ? 4 : 1;
#pragma unroll
  for (int i = 0; i < 8; ++i) {
    const int seg = w * 8 + i;
    const int idx = seg * 64 + lane;
    const int row = idx >> 5, c16 = idx & 31;
    gld_lds16(W + (size_t)(o0 + row) * 256 + ((c16 ^ (row & 7)) * 8), Wl + seg * 512);
    gld_lds16(X + ((size_t)(b * L_) + i0 + row) * 256 + ((c16 ^ (row & 7)) * 8),
              Xl + seg * 512);
  }
  __syncthreads();
  bf16x8 af[8];
#pragma unroll
  for (int kf = 0; kf < 8; ++kf) {
    int row = w * 16 + l15;
    af[kf] = *(const bf16x8*)(Wl + row * 256 + (((kf * 4 + q) ^ (row & 7)) * 8));
  }
  f32x4 acc[4] = {{0.f, 0.f, 0.f, 0.f}, {0.f, 0.f, 0.f, 0.f},
                  {0.f, 0.f, 0.f, 0.f}, {0.f, 0.f, 0.f, 0.f}};
  for (int p = 0; p < NP; ++p) {
    if (p > 0) {
      __syncthreads();  // prev Xl reads done
#pragma unroll
      for (int i = 0; i < 8; ++i) {
        const int seg = w * 8 + i;
        const int idx = seg * 64 + lane;
        const int row = idx >> 5, c16 = idx & 31;
        gld_lds16(X + ((size_t)p * BL + (size_t)(b * L_) + i0 + row) * 256 +
                      ((c16 ^ (row & 7)) * 8),
                  Xl + seg * 512);
      }
      __syncthreads();  // X_p staged
    }
#pragma unroll
    for (int nf = 0; nf < 4; ++nf) {
      f32x4 cacc = acc[nf];
#pragma unroll
      for (int kf = 0; kf < 8; ++kf) {
        int row = nf * 16 + l15;
        bf16x8 bf = *(const bf16x8*)(Xl + row * 256 + (((kf * 4 + q) ^ (row & 7)) * 8));
        cacc = __builtin_amdgcn_mfma_f32_16x16x32_bf16(af[kf], bf, cacc, 0, 0, 0);
      }
      acc[nf] = cacc;
    }
  }
#pragma unroll
  for (int nf = 0; nf < 4; ++nf) {
    const int i = i0 + nf * 16 + l15;
    const int grow = b * L_ + i;
    float sc = 1.0f;
    if (FUSED)
      sc = 1.0f / (ml[grow] + ml[BL + grow] + ml[2 * BL + grow] + ml[3 * BL + grow]);
#pragma unroll
    for (int r = 0; r < 4; ++r) {
      const int o = o0 + w * 16 + q * 4 + r;
      const size_t idx = ((size_t)(b * C_ + o)) * L_ + i;
      out[idx] = acc[nf][r] * sc + bias[o] + xres[idx];
    }
  }
}

extern "C" void kernel_launch(void* const* d_in, const int* in_sizes, int n_in,
                              void* d_out, int out_size, void* d_ws, size_t ws_size,
                              hipStream_t stream) {
  const float* x = (const float*)d_in[0];
  const float* norm_g = (const float*)d_in[1];
  const float* norm_b = (const float*)d_in[2];
  const float* q_w = (const float*)d_in[3];
  const float* q_b = (const float*)d_in[4];
  const float* k_w = (const float*)d_in[5];
  const float* k_b = (const float*)d_in[6];
  const float* v_w = (const float*)d_in[7];
  const float* v_b = (const float*)d_in[8];
  const float* p_w = (const float*)d_in[9];
  const float* p_b = (const float*)d_in[10];
  float* out = (float*)d_out;
  (void)in_sizes; (void)n_in; (void)out_size;

  char* ws = (char*)d_ws;
  const size_t MB = 1u << 20;
  const size_t PSZ = (size_t)BL * 256 * 2;                // 8 MB per partial
  float* stats = (float*)ws;                              // 1 KB
  float* qbs = (float*)(ws + 1024);                       // 1 KB
  unsigned short* wq = (unsigned short*)(ws + 4096);      // 128 KB each
  unsigned short* wk = wq + 65536;
  unsigned short* wv = wk + 65536;
  unsigned short* wp = wv + 65536;
  float* ml = (float*)(ws + 640 * 1024);                  // 256 KB
  unsigned short* ht = (unsigned short*)(ws + 1 * MB);    // 8 MB (later: merged O)
  unsigned short* qt = (unsigned short*)(ws + 9 * MB);    // 8 MB
  unsigned short* kt = (unsigned short*)(ws + 17 * MB);   // 8 MB
  unsigned short* vg = (unsigned short*)(ws + 25 * MB);   // 8 MB V tiles

  const int fused = (ws_size >= 33 * MB + 4 * PSZ) ? 1 : 0;

  unsigned short *o0p, *o1p, *o2p, *o3p;
  if (fused) {
    unsigned short* opcat = (unsigned short*)(ws + 33 * MB);  // 32 MB: [4][BL][256]
    o0p = opcat;
    o1p = opcat + PSZ / 2;
    o2p = opcat + PSZ;
    o3p = opcat + 3 * PSZ / 2;
  } else {
    o0p = (unsigned short*)d_out;               // parts 0,1 in d_out (16 MB of 64)
    o1p = (unsigned short*)d_out + PSZ / 2;
    o2p = (unsigned short*)(ws + 33 * MB);      // parts 2,3 in ws
    o3p = o2p + PSZ / 2;
  }

  init_k<<<256, 256, 0, stream>>>(q_w, k_w, v_w, p_w, q_b, x, wq, wk, wv, wp, qbs, stats);
  gn_apply_k<<<B_ * (L_ / 64), 256, 0, stream>>>(x, stats, norm_g, norm_b, ht);
  qkv_k<<<dim3((B_ * L_) / 64, C_ / 64, 3), 256, 0, stream>>>(ht, wq, wk, wv, qbs, k_b,
                                                              v_b, qt, kt, vg);
  attn_k<<<512, 256, 0, stream>>>(qt, kt, vg, o0p, o1p, o2p, o3p, ml);
  if (fused) {
    proj_k<1><<<dim3(L_ / 64, C_ / 64, B_), 256, 0, stream>>>(o0p, wp, p_b, x, ml, out);
  } else {
    merge_k<<<BL / 8, 256, 0, stream>>>(o0p, o1p, o2p, o3p, ml, ht);
    proj_k<0><<<dim3(L_ / 64, C_ / 64, B_), 256, 0, stream>>>(ht, wp, p_b, x, ml, out);
  }
}

// Round 7
// 220.928 us; speedup vs baseline: 1.0769x; 1.0769x over previous
//
#include <hip/hip_runtime.h>

#define B_ 4
#define C_ 256
#define L_ 4096
#define NG 32
#define CPG 8
#define BL (B_ * L_)               // 16384 token rows
#define KPART 4
#define KEYS_PP (L_ / KPART)       // 1024 keys per partition
#define NIT (KEYS_PP / 32)         // 32 iterations of 32 keys
#define QLOG2E 0.09016844f         // C^-0.5 * log2(e), folded into q_w/q_b

typedef __attribute__((ext_vector_type(8))) __bf16 bf16x8;
typedef __attribute__((ext_vector_type(8))) short s16x8;
typedef __attribute__((ext_vector_type(4))) float f32x4;
typedef __attribute__((ext_vector_type(16))) float f32x16;

__device__ __forceinline__ unsigned short f2bf(float f) {
  unsigned int u = __builtin_bit_cast(unsigned int, f);
  u += 0x7fffu + ((u >> 16) & 1u);
  return (unsigned short)(u >> 16);
}
__device__ __forceinline__ float bf2f(unsigned short u) {
  unsigned int v = ((unsigned int)u) << 16;
  return __builtin_bit_cast(float, v);
}
#if __has_builtin(__builtin_amdgcn_exp2f)
#define EXP2F(x) __builtin_amdgcn_exp2f(x)
#else
#define EXP2F(x) exp2f(x)
#endif

// async global->LDS, 16B/lane; dest = ldsbase + lane*16 (wave-uniform base)
__device__ __forceinline__ void gld_lds16(const void* g, void* l) {
  __builtin_amdgcn_global_load_lds(
      (const __attribute__((address_space(1))) unsigned int*)g,
      (__attribute__((address_space(3))) unsigned int*)l, 16, 0, 0);
}

// sum-reduce over each 16-lane group via DPP
__device__ __forceinline__ float red16_add(float x) {
  int i;
  i = __builtin_amdgcn_update_dpp(0, __builtin_bit_cast(int, x), 0xB1, 0xF, 0xF, false);
  x += __builtin_bit_cast(float, i);
  i = __builtin_amdgcn_update_dpp(0, __builtin_bit_cast(int, x), 0x4E, 0xF, 0xF, false);
  x += __builtin_bit_cast(float, i);
  i = __builtin_amdgcn_update_dpp(0, __builtin_bit_cast(int, x), 0x124, 0xF, 0xF, false);
  x += __builtin_bit_cast(float, i);
  i = __builtin_amdgcn_update_dpp(0, __builtin_bit_cast(int, x), 0x128, 0xF, 0xF, false);
  x += __builtin_bit_cast(float, i);
  return x;
}

// ------- init: weight cvt (blocks 0..127) + GN stats (blocks 128..255) -------
__global__ __launch_bounds__(256) void init_k(const float* __restrict__ qw,
                                              const float* __restrict__ kw,
                                              const float* __restrict__ vw,
                                              const float* __restrict__ pw,
                                              const float* __restrict__ qb,
                                              const float* __restrict__ x,
                                              unsigned short* __restrict__ wq,
                                              unsigned short* __restrict__ wk,
                                              unsigned short* __restrict__ wv,
                                              unsigned short* __restrict__ wp,
                                              float* __restrict__ qbs,
                                              float* __restrict__ stats) {
  const int bid = blockIdx.x;
  const int t = threadIdx.x;
  if (bid < 128) {
    const int m = bid >> 5;
    const int blk = bid & 31;
    const float* src = (m == 0) ? qw : (m == 1) ? kw : (m == 2) ? vw : pw;
    unsigned short* dst = (m == 0) ? wq : (m == 1) ? wk : (m == 2) ? wv : wp;
    const float sc = (m == 0) ? QLOG2E : 1.0f;
    const int base = (blk * 256 + t) * 8;
    f32x4 a = *(const f32x4*)(src + base);
    f32x4 b = *(const f32x4*)(src + base + 4);
    s16x8 o;
#pragma unroll
    for (int j = 0; j < 4; ++j) {
      o[j] = (short)f2bf(a[j] * sc);
      o[4 + j] = (short)f2bf(b[j] * sc);
    }
    *(s16x8*)(dst + base) = o;
    if (m == 0 && blk == 0) qbs[t] = qb[t] * QLOG2E;
  } else {
    const int bg = bid - 128;
    const float* base = x + (size_t)bg * (CPG * L_);
    float s = 0.f, ss = 0.f;
#pragma unroll
    for (int i = 0; i < 32; ++i) {
      f32x4 v = *(const f32x4*)(base + (size_t)(t + i * 256) * 4);
#pragma unroll
      for (int j = 0; j < 4; ++j) { s += v[j]; ss += v[j] * v[j]; }
    }
#pragma unroll
    for (int d = 1; d < 64; d <<= 1) {
      s += __shfl_xor(s, d, 64);
      ss += __shfl_xor(ss, d, 64);
    }
    __shared__ float red[8];
    if ((t & 63) == 0) { red[(t >> 6) * 2] = s; red[(t >> 6) * 2 + 1] = ss; }
    __syncthreads();
    if (t == 0) {
      float S = red[0] + red[2] + red[4] + red[6];
      float SS = red[1] + red[3] + red[5] + red[7];
      const float inv_n = 1.f / (float)(CPG * L_);
      float mean = S * inv_n;
      float var = SS * inv_n - mean * mean;
      stats[bg * 2] = mean;
      stats[bg * 2 + 1] = rsqrtf(var + 1e-6f);
    }
  }
}

// ------------- GroupNorm apply + transpose -> ht[B*L, C] bf16 -------------
__global__ __launch_bounds__(256) void gn_apply_k(const float* __restrict__ x,
                                                  const float* __restrict__ stats,
                                                  const float* __restrict__ gam,
                                                  const float* __restrict__ bet,
                                                  unsigned short* __restrict__ ht) {
  __shared__ unsigned short tile[64 * 256];
  const int blk = blockIdx.x;
  const int b = blk >> 6;
  const int l0 = (blk & 63) * 64;
  const int t = threadIdx.x;
  const int c = t;
  const float mean = stats[(b * NG + (c >> 3)) * 2];
  const float rstd = stats[(b * NG + (c >> 3)) * 2 + 1];
  const float sc = rstd * gam[c];
  const float sb = bet[c] - mean * sc;
  const float* row = x + ((size_t)(b * C_ + c)) * L_ + l0;
#pragma unroll
  for (int v = 0; v < 16; ++v) {
    f32x4 f = *(const f32x4*)(row + v * 4);
#pragma unroll
    for (int j = 0; j < 4; ++j) tile[(v * 4 + j) * 256 + c] = f2bf(f[j] * sc + sb);
  }
  __syncthreads();
#pragma unroll
  for (int i = 0; i < 8; ++i) {
    int id = t + i * 256;
    int l = id >> 5, off = id & 31;
    *(s16x8*)(ht + ((size_t)(b * L_) + l0 + l) * 256 + off * 8) =
        *(const s16x8*)(tile + l * 256 + off * 8);
  }
}

// ---- QKV fused: z=0 Q->qt rows, z=1 K->kt rows, z=2 V->vg swizzled tiles ----
__global__ __launch_bounds__(256) void qkv_k(const unsigned short* __restrict__ ht,
                                             const unsigned short* __restrict__ wq,
                                             const unsigned short* __restrict__ wk,
                                             const unsigned short* __restrict__ wv,
                                             const float* __restrict__ qbs,
                                             const float* __restrict__ kbias,
                                             const float* __restrict__ vbias,
                                             unsigned short* __restrict__ qt,
                                             unsigned short* __restrict__ kt,
                                             unsigned short* __restrict__ vg) {
  __shared__ unsigned short Al[64 * 256];
  __shared__ unsigned short Wl[64 * 256];
  const int z = blockIdx.z;
  const unsigned short* W = (z == 0) ? wq : (z == 1) ? wk : wv;
  const float* bias = (z == 0) ? qbs : (z == 1) ? kbias : vbias;
  const int m0 = blockIdx.x * 64;
  const int n0 = blockIdx.y * 64;
  const int t = threadIdx.x;
  const int w = t >> 6, lane = t & 63, l15 = lane & 15, q = lane >> 4;
#pragma unroll
  for (int i = 0; i < 8; ++i) {
    const int seg = w * 8 + i;
    const int idx = seg * 64 + lane;
    const int row = idx >> 5, c16 = idx & 31;
    gld_lds16(ht + (size_t)(m0 + row) * 256 + ((c16 ^ (row & 7)) * 8), Al + seg * 512);
    gld_lds16(W + (size_t)(n0 + row) * 256 + ((c16 ^ (row & 7)) * 8), Wl + seg * 512);
  }
  __syncthreads();
  bf16x8 af[8];
#pragma unroll
  for (int kf = 0; kf < 8; ++kf) {
    int row = w * 16 + l15;
    af[kf] = *(const bf16x8*)(Al + row * 256 + (((kf * 4 + q) ^ (row & 7)) * 8));
  }
  f32x4 acc[4];
#pragma unroll
  for (int nf = 0; nf < 4; ++nf) {
    f32x4 cacc = {0.f, 0.f, 0.f, 0.f};
#pragma unroll
    for (int kf = 0; kf < 8; ++kf) {
      int row = nf * 16 + l15;
      bf16x8 bf = *(const bf16x8*)(Wl + row * 256 + (((kf * 4 + q) ^ (row & 7)) * 8));
      cacc = __builtin_amdgcn_mfma_f32_16x16x32_bf16(af[kf], bf, cacc, 0, 0, 0);
    }
    acc[nf] = cacc;
  }
  unsigned short* Ct = (z == 0) ? qt : kt;
#pragma unroll
  for (int nf = 0; nf < 4; ++nf) {
    const int n = n0 + nf * 16 + l15;
    const float bs = bias[n];
#pragma unroll
    for (int r = 0; r < 4; ++r) {
      const int m = m0 + w * 16 + q * 4 + r;
      const float v = acc[nf][r] + bs;
      if (z < 2) {
        Ct[(size_t)m * 256 + n] = f2bf(v);
      } else {
        // V tile layout: [b][jt(32-key tiles)][c][(qc ^ ((c>>1)&3))*8 + pos]
        const int b = m >> 12, i = m & (L_ - 1);
        const int jt = i >> 5, jj = i & 31;
        const int qc = jj >> 3, pos = jj & 7;
        vg[((size_t)(b * 128 + jt)) * 8192 + n * 32 + ((qc ^ ((n >> 1) & 3)) * 8) + pos] =
            f2bf(v);
      }
    }
  }
}

// ------- Flash attention v7: R4 structure + double-buffered K/V, 1 barrier/iter -------
// Qt,Kt: [B*L, C] bf16 rows (Q pre-scaled by QLOG2E); Vg: swizzled 32-key tiles.
// p = exp2(s); partial O (unnormalized) + row-sums l per partition.
__global__ __launch_bounds__(256, 2) void attn_k(const unsigned short* __restrict__ Qt,
                                                 const unsigned short* __restrict__ Kt,
                                                 const unsigned short* __restrict__ Vg,
                                                 unsigned short* __restrict__ o0p,
                                                 unsigned short* __restrict__ o1p,
                                                 unsigned short* __restrict__ o2p,
                                                 unsigned short* __restrict__ o3p,
                                                 float* __restrict__ ml) {
  __shared__ unsigned short Kl[2][32 * 256];   // 2 x 16 KB [keyrow][chunk ^ (row&7)]
  __shared__ unsigned short Vl[2][256 * 32];   // 2 x 16 KB [c][qc swz][8]
  __shared__ unsigned short Pl[4 * 32 * 40];   // per-wave [32 q][32 k], rows pad 40
  const int bid = blockIdx.x;
  const int g = bid & 15;                      // co-locates (b,part) per XCD
  const int b = g >> 2, part = g & 3;
  const int qi = bid >> 4;                     // 0..31 q-tile within batch
  const int t = threadIdx.x;
  const int w = t >> 6, lane = t & 63;
  const int l15 = lane & 15, q = lane >> 4;
  const int l31 = lane & 31, h = lane >> 5;

  const int qb0 = b * L_ + qi * 128;
  const int qrow0 = qb0 + w * 32;              // wave's first query row (global)
  bf16x8 qf[2][8];
#pragma unroll
  for (int mi = 0; mi < 2; ++mi)
#pragma unroll
    for (int kf = 0; kf < 8; ++kf)
      qf[mi][kf] =
          *(const bf16x8*)(Qt + ((size_t)(qrow0 + mi * 16 + l15)) * 256 + kf * 32 + q * 8);

  f32x16 oacc[8];
#pragma unroll
  for (int nf = 0; nf < 8; ++nf)
#pragma unroll
    for (int gg = 0; gg < 16; ++gg) oacc[nf][gg] = 0.f;
  float ls0[4] = {0.f, 0.f, 0.f, 0.f}, ls1[4] = {0.f, 0.f, 0.f, 0.f};

  const unsigned short* kbase = Kt + ((size_t)(b * L_ + part * KEYS_PP)) * 256;
  const unsigned short* vbase = Vg + ((size_t)(b * 128 + part * 32)) * 8192;
  unsigned short* Pw = Pl + w * 1280;

  // prologue: stage tile 0 into buffer 0
#pragma unroll
  for (int i = 0; i < 4; ++i) {
    const int seg = w * 4 + i;
    const int idx = seg * 64 + lane;
    const int row = idx >> 5, c16 = idx & 31;
    gld_lds16(kbase + (size_t)row * 256 + ((c16 ^ (row & 7)) * 8), &Kl[0][0] + seg * 512);
    gld_lds16(vbase + (size_t)idx * 8, &Vl[0][0] + seg * 512);
  }

  for (int it = 0; it < NIT; ++it) {
    __syncthreads();  // drains prefetch issued one iteration ago (mostly complete)
    // prefetch tile it+1 into the other buffer; consumed after next barrier
    if (it + 1 < NIT) {
      const unsigned short* ksrc = kbase + (size_t)((it + 1) * 32) * 256;
      const unsigned short* vsrc = vbase + (size_t)(it + 1) * 8192;
      unsigned short* kd = &Kl[(it + 1) & 1][0];
      unsigned short* vd = &Vl[(it + 1) & 1][0];
#pragma unroll
      for (int i = 0; i < 4; ++i) {
        const int seg = w * 4 + i;
        const int idx = seg * 64 + lane;
        const int row = idx >> 5, c16 = idx & 31;
        gld_lds16(ksrc + (size_t)row * 256 + ((c16 ^ (row & 7)) * 8), kd + seg * 512);
        gld_lds16(vsrc + (size_t)idx * 8, vd + seg * 512);
      }
    }
    const unsigned short* Kb = &Kl[it & 1][0];
    const unsigned short* Vb = &Vl[it & 1][0];

    // QK^T: wave's 32 queries x 32 keys
    f32x4 s00 = {0.f, 0.f, 0.f, 0.f}, s01 = s00, s10 = s00, s11 = s00;
#pragma unroll
    for (int kf = 0; kf < 8; ++kf) {
      const int ch = ((kf * 4 + q) ^ (l15 & 7)) * 8;
      bf16x8 kb0 = *(const bf16x8*)(Kb + l15 * 256 + ch);
      bf16x8 kb1 = *(const bf16x8*)(Kb + (16 + l15) * 256 + ch);
      s00 = __builtin_amdgcn_mfma_f32_16x16x32_bf16(qf[0][kf], kb0, s00, 0, 0, 0);
      s01 = __builtin_amdgcn_mfma_f32_16x16x32_bf16(qf[0][kf], kb1, s01, 0, 0, 0);
      s10 = __builtin_amdgcn_mfma_f32_16x16x32_bf16(qf[1][kf], kb0, s10, 0, 0, 0);
      s11 = __builtin_amdgcn_mfma_f32_16x16x32_bf16(qf[1][kf], kb1, s11, 0, 0, 0);
    }
    // p = exp2(s); accumulate row-sum partials; P -> per-wave LDS (same iter)
#pragma unroll
    for (int r = 0; r < 4; ++r) {
      float p00 = EXP2F(s00[r]), p01 = EXP2F(s01[r]);
      float p10 = EXP2F(s10[r]), p11 = EXP2F(s11[r]);
      ls0[r] += p00 + p01;
      ls1[r] += p10 + p11;
      Pw[(q * 4 + r) * 40 + l15] = f2bf(p00);
      Pw[(q * 4 + r) * 40 + 16 + l15] = f2bf(p01);
      Pw[(16 + q * 4 + r) * 40 + l15] = f2bf(p10);
      Pw[(16 + q * 4 + r) * 40 + 16 + l15] = f2bf(p11);
    }
    // PV: 32x32x16, two 16-key halves; wave owns its 32 q x all 256 channels
    bf16x8 pa0 = *(const bf16x8*)(Pw + l31 * 40 + h * 8);
    bf16x8 pa1 = *(const bf16x8*)(Pw + l31 * 40 + 16 + h * 8);
#pragma unroll
    for (int nf = 0; nf < 8; ++nf) {
      const int c = nf * 32 + l31;
      bf16x8 v0 = *(const bf16x8*)(Vb + c * 32 + ((h ^ ((c >> 1) & 3)) * 8));
      bf16x8 v1 = *(const bf16x8*)(Vb + c * 32 + (((2 + h) ^ ((c >> 1) & 3)) * 8));
      oacc[nf] = __builtin_amdgcn_mfma_f32_32x32x16_bf16(pa0, v0, oacc[nf], 0, 0, 0);
      oacc[nf] = __builtin_amdgcn_mfma_f32_32x32x16_bf16(pa1, v1, oacc[nf], 0, 0, 0);
    }
  }

  // write partial O (32x32 C-layout per tile: col=l31, row=(g&3)+8*(g>>2)+4*h)
  unsigned short* opb = (part == 0) ? o0p : (part == 1) ? o1p : (part == 2) ? o2p : o3p;
#pragma unroll
  for (int nf = 0; nf < 8; ++nf)
#pragma unroll
    for (int gg = 0; gg < 16; ++gg) {
      const int row = (gg & 3) + 8 * (gg >> 2) + 4 * h;
      opb[(size_t)(qrow0 + row) * 256 + nf * 32 + l31] = f2bf(oacc[nf][gg]);
    }
  // row-sums (wave's own 32 queries)
#pragma unroll
  for (int r = 0; r < 4; ++r) {
    ls0[r] = red16_add(ls0[r]);
    ls1[r] = red16_add(ls1[r]);
  }
  if (l15 == 0) {
    float* mlp = ml + (size_t)part * BL;
#pragma unroll
    for (int r = 0; r < 4; ++r) {
      mlp[qrow0 + q * 4 + r] = ls0[r];
      mlp[qrow0 + 16 + q * 4 + r] = ls1[r];
    }
  }
}

// ------------- merge 4 partials -> Om [B*L, C] bf16 -------------
__global__ __launch_bounds__(256) void merge_k(const unsigned short* __restrict__ o0p,
                                               const unsigned short* __restrict__ o1p,
                                               const unsigned short* __restrict__ o2p,
                                               const unsigned short* __restrict__ o3p,
                                               const float* __restrict__ ml,
                                               unsigned short* __restrict__ Om) {
  const int row = blockIdx.x * 8 + (threadIdx.x >> 5);
  const int c8 = threadIdx.x & 31;
  const float inv = 1.0f / (ml[row] + ml[BL + row] + ml[2 * BL + row] + ml[3 * BL + row]);
  const size_t off = (size_t)row * 256 + c8 * 8;
  s16x8 v0 = *(const s16x8*)(o0p + off);
  s16x8 v1 = *(const s16x8*)(o1p + off);
  s16x8 v2 = *(const s16x8*)(o2p + off);
  s16x8 v3 = *(const s16x8*)(o3p + off);
  s16x8 o;
#pragma unroll
  for (int j = 0; j < 8; ++j)
    o[j] = (short)f2bf((bf2f((unsigned short)v0[j]) + bf2f((unsigned short)v1[j]) +
                        bf2f((unsigned short)v2[j]) + bf2f((unsigned short)v3[j])) *
                       inv);
  *(s16x8*)(Om + off) = o;
}

// ---- proj: out[b,o,i] = x + bias[o] + sum_k W[o,k]*Om[b*L+i,k] ----
__global__ __launch_bounds__(256) void proj_k(const unsigned short* __restrict__ X,
                                              const unsigned short* __restrict__ W,
                                              const float* __restrict__ bias,
                                              const float* __restrict__ xres,
                                              float* __restrict__ out) {
  __shared__ unsigned short Wl[64 * 256];
  __shared__ unsigned short Xl[64 * 256];
  const int i0 = blockIdx.x * 64;
  const int o0 = blockIdx.y * 64;
  const int b = blockIdx.z;
  const int t = threadIdx.x;
  const int w = t >> 6, lane = t & 63, l15 = lane & 15, q = lane >> 4;
#pragma unroll
  for (int i = 0; i < 8; ++i) {
    const int seg = w * 8 + i;
    const int idx = seg * 64 + lane;
    const int row = idx >> 5, c16 = idx & 31;
    gld_lds16(W + (size_t)(o0 + row) * 256 + ((c16 ^ (row & 7)) * 8), Wl + seg * 512);
    gld_lds16(X + ((size_t)(b * L_) + i0 + row) * 256 + ((c16 ^ (row & 7)) * 8),
              Xl + seg * 512);
  }
  __syncthreads();
  bf16x8 af[8];
#pragma unroll
  for (int kf = 0; kf < 8; ++kf) {
    int row = w * 16 + l15;
    af[kf] = *(const bf16x8*)(Wl + row * 256 + (((kf * 4 + q) ^ (row & 7)) * 8));
  }
  f32x4 acc[4];
#pragma unroll
  for (int nf = 0; nf < 4; ++nf) {
    f32x4 cacc = {0.f, 0.f, 0.f, 0.f};
#pragma unroll
    for (int kf = 0; kf < 8; ++kf) {
      int row = nf * 16 + l15;
      bf16x8 bf = *(const bf16x8*)(Xl + row * 256 + (((kf * 4 + q) ^ (row & 7)) * 8));
      cacc = __builtin_amdgcn_mfma_f32_16x16x32_bf16(af[kf], bf, cacc, 0, 0, 0);
    }
    acc[nf] = cacc;
  }
#pragma unroll
  for (int nf = 0; nf < 4; ++nf) {
    const int i = i0 + nf * 16 + l15;
#pragma unroll
    for (int r = 0; r < 4; ++r) {
      const int o = o0 + w * 16 + q * 4 + r;
      const size_t idx = ((size_t)(b * C_ + o)) * L_ + i;
      out[idx] = acc[nf][r] + bias[o] + xres[idx];
    }
  }
}

extern "C" void kernel_launch(void* const* d_in, const int* in_sizes, int n_in,
                              void* d_out, int out_size, void* d_ws, size_t ws_size,
                              hipStream_t stream) {
  const float* x = (const float*)d_in[0];
  const float* norm_g = (const float*)d_in[1];
  const float* norm_b = (const float*)d_in[2];
  const float* q_w = (const float*)d_in[3];
  const float* q_b = (const float*)d_in[4];
  const float* k_w = (const float*)d_in[5];
  const float* k_b = (const float*)d_in[6];
  const float* v_w = (const float*)d_in[7];
  const float* v_b = (const float*)d_in[8];
  const float* p_w = (const float*)d_in[9];
  const float* p_b = (const float*)d_in[10];
  float* out = (float*)d_out;
  (void)in_sizes; (void)n_in; (void)out_size; (void)ws_size;

  char* ws = (char*)d_ws;
  const size_t MB = 1u << 20;
  const size_t PSZ = (size_t)BL * 256 * 2;                // 8.39 MB per partial
  float* stats = (float*)ws;                              // 1 KB
  float* qbs = (float*)(ws + 1024);                       // 1 KB
  unsigned short* wq = (unsigned short*)(ws + 4096);      // 128 KB each
  unsigned short* wk = wq + 65536;
  unsigned short* wv = wk + 65536;
  unsigned short* wp = wv + 65536;
  float* ml = (float*)(ws + 640 * 1024);                  // 256 KB
  unsigned short* ht = (unsigned short*)(ws + 1 * MB);    // 8 MB (later: merged O)
  unsigned short* qt = (unsigned short*)(ws + 9 * MB);    // 8 MB
  unsigned short* kt = (unsigned short*)(ws + 17 * MB);   // 8 MB
  unsigned short* vg = (unsigned short*)(ws + 25 * MB);   // 8 MB V tiles
  unsigned short* o0p = (unsigned short*)d_out;           // parts 0,1 fill d_out exactly
  unsigned short* o1p = o0p + PSZ / 2;
  unsigned short* o2p = (unsigned short*)(ws + 33 * MB);  // parts 2,3 in ws
  unsigned short* o3p = o2p + PSZ / 2;

  init_k<<<256, 256, 0, stream>>>(q_w, k_w, v_w, p_w, q_b, x, wq, wk, wv, wp, qbs, stats);
  gn_apply_k<<<B_ * (L_ / 64), 256, 0, stream>>>(x, stats, norm_g, norm_b, ht);
  qkv_k<<<dim3((B_ * L_) / 64, C_ / 64, 3), 256, 0, stream>>>(ht, wq, wk, wv, qbs, k_b,
                                                              v_b, qt, kt, vg);
  attn_k<<<512, 256, 0, stream>>>(qt, kt, vg, o0p, o1p, o2p, o3p, ml);
  merge_k<<<BL / 8, 256, 0, stream>>>(o0p, o1p, o2p, o3p, ml, ht);
  proj_k<<<dim3(L_ / 64, C_ / 64, B_), 256, 0, stream>>>(ht, wp, p_b, x, out);
}